// Round 10
// baseline (116.680 us; speedup 1.0000x reference)
//
#include <hip/hip_runtime.h>

// ---------------------------------------------------------------------------
// ParC-ConvNeXt block, MI355X (gfx950).
//   out = x + gamma * MLP(LN(NHWC(concat(ParC_H(x[:192]), ParC_W(x[192:])))))
// Round 9 -> 10: MX-scaled fp8 MFMA (mfma_scale_f32_32x32x64_f8f6f4, unit
//   E8M0 scales = plain fp8 math at ~4.7 PF, 2.3x the non-scaled fp8 rate;
//   4 MFMA instr/step instead of 32 -> issue/VALU load way down).
//   Packed layouts now LINEAR-k per 64B row (chunk-16B XOR swizzle kept):
//   W1P/W2P/YLNP/HID all [kt][row][64B], chunk q -> q ^ ((row>>1)&3).
//   GEMM structure kept: BM=BN=128, 256 thr (4 waves 2x2, wave tile 64x64 =
//   2x2 32x32 frags), NB=3 ring, DEPTH=2 counted vmcnt, raw barriers,
//   setprio, XCD swizzle. LDS 48KB -> 3 blocks/CU.
// ---------------------------------------------------------------------------

typedef __attribute__((ext_vector_type(8))) short short8;
typedef __attribute__((ext_vector_type(4))) float f32x4;
typedef __attribute__((ext_vector_type(16))) float f32x16;
typedef __attribute__((ext_vector_type(4))) int int4v;
typedef __attribute__((ext_vector_type(8))) int i32x8;

__device__ __forceinline__ float bf2f(unsigned short u) {
  union { unsigned int i; float f; } v; v.i = ((unsigned int)u) << 16; return v.f;
}
__device__ __forceinline__ unsigned short f2bf(float f) {
  union { float f; unsigned int i; } v; v.f = f;
  unsigned int r = v.i + 0x7FFFu + ((v.i >> 16) & 1u);
  return (unsigned short)(r >> 16);
}

#if defined(__has_builtin)
#if __has_builtin(__builtin_amdgcn_global_load_lds)
#define HAS_GLL 1
#endif
#endif
#ifndef HAS_GLL
#define HAS_GLL 0
#endif

#if HAS_GLL
__device__ __forceinline__ void gload16(const void* g, void* l) {
  __builtin_amdgcn_global_load_lds((const __attribute__((address_space(1))) void*)g,
                                   (__attribute__((address_space(3))) void*)l, 16, 0, 0);
}
#else
__device__ __forceinline__ void gload16(const void* g, void* l) {
  *(f32x4*)l = *(const f32x4*)g;
}
#endif

template <int N>
__device__ __forceinline__ void wait_vm() {
  asm volatile("s_waitcnt vmcnt(%0)" :: "n"(N) : "memory");
}
__device__ __forceinline__ void barrier_raw() {
  __builtin_amdgcn_s_barrier();
  __builtin_amdgcn_sched_barrier(0);
}

// fast sigmoid-GELU: h * sigmoid(1.702h); exp2/rcp HW approx (1e-6 slack)
__device__ __forceinline__ float fast_gelu(float h) {
  const float e = __builtin_amdgcn_exp2f(-2.4554005f * h);  // 1.702/ln2 folded
  return h * __builtin_amdgcn_rcpf(1.f + e);
}

// pack 4 consecutive-k f32 into fp8 dword
__device__ __forceinline__ int pk4(float a, float b, float c, float d) {
  int r = __builtin_amdgcn_cvt_pk_fp8_f32(a, b, 0, false);
  return __builtin_amdgcn_cvt_pk_fp8_f32(c, d, r, true);
}

#define SCL1 0x7F7F7F7F  // E8M0 = 127 -> 2^0 in all 4 bytes

// --------------------------- weight pack -----------------------------------
// 64B-row layout: row r holds k 0..63 LINEAR; 16B chunk q at phys q^((r>>1)&3).
// blocks 0..35 : w1 [384][1536] -> W1P [kt 6][h 1536][64B]   (k = input dim)
// blocks 36..59: w2 [1536][384] -> W2P [kt 24][c 384][64B]   (k = hidden dim)
__global__ __launch_bounds__(256) void pack_kernel(
    const float* __restrict__ w1, const float* __restrict__ w2,
    char* __restrict__ w1p, char* __restrict__ w2p) {
  const int t = threadIdx.x;
  const int bid = blockIdx.x;
  float v[64];
  if (bid < 36) {
    const int kt = bid % 6, hg = bid / 6;
    const int h = hg * 256 + t;
    #pragma unroll
    for (int k = 0; k < 64; ++k) v[k] = w1[(size_t)(kt * 64 + k) * 1536 + h];
    const int swz = (h >> 1) & 3;
    char* rowp = w1p + ((size_t)(kt * 1536 + h)) * 64;
    #pragma unroll
    for (int k0 = 0; k0 < 64; k0 += 4) {
      const int chunk = (k0 >> 4) ^ swz;
      *(int*)(rowp + chunk * 16 + (k0 & 12)) = pk4(v[k0], v[k0 + 1], v[k0 + 2], v[k0 + 3]);
    }
  } else {
    const int kt = bid - 36;
    for (int c = t; c < 384; c += 256) {
      #pragma unroll
      for (int k = 0; k < 64; ++k) v[k] = w2[(size_t)(kt * 64 + k) * 384 + c];
      const int swz = (c >> 1) & 3;
      char* rowp = w2p + ((size_t)(kt * 384 + c)) * 64;
      #pragma unroll
      for (int k0 = 0; k0 < 64; k0 += 4) {
        const int chunk = (k0 >> 4) ^ swz;
        *(int*)(rowp + chunk * 16 + (k0 & 12)) = pk4(v[k0], v[k0 + 1], v[k0 + 2], v[k0 + 3]);
      }
    }
  }
}

// ------------------------------- ParC conv ---------------------------------
__global__ __launch_bounds__(256) void conv_kernel(
    const float* __restrict__ x,
    const float* __restrict__ pe_h, const float* __restrict__ w_h, const float* __restrict__ b_h,
    const float* __restrict__ pe_w, const float* __restrict__ w_w, const float* __restrict__ b_w,
    unsigned short* __restrict__ convout) {
  __shared__ float wt_s[8][32], pe_s[8][32], pc_s[8][32];
  const int t = threadIdx.x;
  const int bid = blockIdx.x;
  const int b = bid / 48, g = bid % 48;
  const int c0 = g << 3;
  const bool ish = (c0 < 192);
  const int cl = t >> 5, q = t & 31;
  {
    const int c = c0 + cl;
    if (ish) { wt_s[cl][q] = w_h[(c << 5) + q];           pe_s[cl][q] = pe_h[(c << 5) + q]; }
    else     { const int cc = c - 192;
               wt_s[cl][q] = w_w[(cc << 5) + q];          pe_s[cl][q] = pe_w[(cc << 5) + q]; }
  }
  __syncthreads();
  {
    float s = ish ? b_h[c0 + cl] : b_w[c0 + cl - 192];
    #pragma unroll
    for (int i = 0; i < 32; ++i) s += pe_s[cl][(q + i) & 31] * wt_s[cl][i];
    pc_s[cl][q] = s;
  }
  __syncthreads();
  const float* xp = x + ((size_t)(b * 384 + c0 + cl) << 10);
  float col[32];
  if (ish) {
    #pragma unroll
    for (int j = 0; j < 32; ++j) col[j] = xp[(j << 5) + q];
  } else {
    const float* rp = xp + (q << 5);
    #pragma unroll
    for (int j4 = 0; j4 < 8; ++j4) {
      f32x4 v = *(const f32x4*)&rp[j4 << 2];
      col[j4 * 4 + 0] = v[0]; col[j4 * 4 + 1] = v[1];
      col[j4 * 4 + 2] = v[2]; col[j4 * 4 + 3] = v[3];
    }
  }
  float wr[32];
  #pragma unroll
  for (int i = 0; i < 32; ++i) wr[i] = wt_s[cl][i];
  float o[32];
  #pragma unroll
  for (int oo = 0; oo < 32; ++oo) o[oo] = pc_s[cl][oo];
  #pragma unroll
  for (int i = 0; i < 32; ++i)
    #pragma unroll
    for (int oo = 0; oo < 32; ++oo)
      o[oo] = fmaf(col[(oo + i) & 31], wr[i], o[oo]);
  unsigned short* op = convout + ((size_t)(b * 384 + c0 + cl) << 10);
  if (ish) {
    #pragma unroll
    for (int oo = 0; oo < 32; ++oo) op[(oo << 5) + q] = f2bf(o[oo]);
  } else {
    #pragma unroll
    for (int j8 = 0; j8 < 4; ++j8) {
      short8 p;
      #pragma unroll
      for (int j = 0; j < 8; ++j) p[j] = (short)f2bf(o[j8 * 8 + j]);
      *(short8*)&op[(q << 5) + j8 * 8] = p;
    }
  }
}

// --------------------------- LayerNorm stats -------------------------------
__global__ __launch_bounds__(256) void ln_stats_kernel(
    const unsigned short* __restrict__ conv,
    float* __restrict__ mu, float* __restrict__ rs) {
  __shared__ float sums[4][64], sqs[4][64];
  const int tid = threadIdx.x;
  const int lane = tid & 63;
  const int w = tid >> 6;
  const int px = blockIdx.x * 64 + lane;
  const int b = px >> 10, hw = px & 1023;
  const unsigned short* cp = conv + (((size_t)(b * 384 + w * 96)) << 10) + hw;
  float s = 0.f, ss = 0.f;
  #pragma unroll 8
  for (int k = 0; k < 96; ++k) {
    float v = bf2f(cp[(size_t)k << 10]);
    s += v; ss = fmaf(v, v, ss);
  }
  sums[w][lane] = s; sqs[w][lane] = ss;
  __syncthreads();
  if (tid < 64) {
    const float st = sums[0][tid] + sums[1][tid] + sums[2][tid] + sums[3][tid];
    const float sst = sqs[0][tid] + sqs[1][tid] + sqs[2][tid] + sqs[3][tid];
    const float m = st * (1.f / 384.f);
    const float var = sst * (1.f / 384.f) - m * m;
    mu[blockIdx.x * 64 + tid] = m;
    rs[blockIdx.x * 64 + tid] = rsqrtf(var + 1e-6f);
  }
}

// --------------------------- LayerNorm pack --------------------------------
// grid (128, 6): thread = one (px, kt). fp8 YLNP [kt 6][px 32768][64B],
// linear-k rows, chunk XOR swizzle.
__global__ __launch_bounds__(256) void ln_pack_kernel(
    const unsigned short* __restrict__ conv,
    const float* __restrict__ mu, const float* __restrict__ rs,
    char* __restrict__ ylnp,
    const float* __restrict__ ln_w, const float* __restrict__ ln_b) {
  __shared__ float lw[64], lb[64];
  const int kt = blockIdx.y;
  const int t = threadIdx.x;
  if (t < 64) { lw[t] = ln_w[kt * 64 + t]; lb[t] = ln_b[kt * 64 + t]; }
  __syncthreads();
  const int px = blockIdx.x * 256 + t;
  const int b = px >> 10, hw = px & 1023;
  const unsigned short* cp = conv + (((size_t)(b * 384 + kt * 64)) << 10) + hw;
  const float m = mu[px], r = rs[px];
  float ov[64];
  #pragma unroll
  for (int k = 0; k < 64; ++k) {
    const float v = bf2f(cp[(size_t)k << 10]);
    ov[k] = (v - m) * r * lw[k] + lb[k];
  }
  const int swz = (px >> 1) & 3;
  char* rowp = ylnp + ((size_t)(kt * 32768 + px)) * 64;
  #pragma unroll
  for (int q = 0; q < 4; ++q) {
    int4v d;
    d[0] = pk4(ov[q * 16 + 0],  ov[q * 16 + 1],  ov[q * 16 + 2],  ov[q * 16 + 3]);
    d[1] = pk4(ov[q * 16 + 4],  ov[q * 16 + 5],  ov[q * 16 + 6],  ov[q * 16 + 7]);
    d[2] = pk4(ov[q * 16 + 8],  ov[q * 16 + 9],  ov[q * 16 + 10], ov[q * 16 + 11]);
    d[3] = pk4(ov[q * 16 + 12], ov[q * 16 + 13], ov[q * 16 + 14], ov[q * 16 + 15]);
    *(int4v*)(rowp + ((q ^ swz) << 4)) = d;
  }
}

// --------------------------- GEMM (MX fp8) ---------------------------------
// mfma_scale_f32_32x32x64_f8f6f4, unit scales. Wave tile 64x64 = 2x2 32-frags
// (acc f32x16[2][2]); 4 MFMA per K=64 step. A [AROWS][64B/kt], B rows via
// bstride/boff. BM=BN=128, 256 thr, NB=3 ring DEPTH=2, counted vmcnt.
// EPI 0 (GEMM1): HID fp8 [kt 24][hstride px][64B], gelu+pk4 dword stores.
// EPI 1 (GEMM2): out(NCHW f32) = x + gamma*(acc+b2), px-contiguous 128B runs.
template <int EPI, int KDIM, int AROWS>
__global__ __launch_bounds__(256, 3) void gemm_kernel(
    const char* __restrict__ Ab, const char* __restrict__ Bb,
    char* __restrict__ Hout8, const float* __restrict__ bias,
    const float* __restrict__ gamma, const float* __restrict__ xres,
    float* __restrict__ out, int px0, int bstride, int boff, int hstride,
    int nwg, int nx) {
  extern __shared__ char lds[];
  constexpr int BM = 128, BN = 128;
  constexpr int NB = 3, DEPTH = 2;
  constexpr int NT = KDIM / 64;
  constexpr int SLOT = (BM + BN) * 64;       // 16384
  constexpr int CH = 4;                      // vm ops per stage
  const int tid = threadIdx.x;
  const int lane = tid & 63;
  const int wid = tid >> 6;
  const int wm = wid >> 1, wn = wid & 1;
  const int lane31 = lane & 31;
  const int kh = lane >> 5;                  // k-half (32B) / D row-offset 4*kh
  // bijective XCD swizzle; consecutive logical ids share the B (px) strip
  const int bid = blockIdx.x;
  const int q = nwg >> 3, r = nwg & 7;
  const int xcd = bid & 7, idx = bid >> 3;
  const int lg = (xcd < r ? xcd * (q + 1) : r * (q + 1) + (xcd - r) * q) + idx;
  const int xb = lg % nx, yb = lg / nx;
  const int arow0 = xb * BM;
  const int brow0 = yb * BN;

  f32x16 acc[2][2] = {};

  // hoisted LDS byte offsets (slot-relative)
  int aoff[2][2], boffl[2][2];
  #pragma unroll
  for (int m = 0; m < 2; ++m) {
    const int row = wm * 64 + m * 32 + lane31;
    const int s = (row >> 1) & 3;
    aoff[m][0] = row * 64 + (((2 * kh + 0) ^ s) << 4);
    aoff[m][1] = row * 64 + (((2 * kh + 1) ^ s) << 4);
  }
  #pragma unroll
  for (int n = 0; n < 2; ++n) {
    const int row = wn * 64 + n * 32 + lane31;
    const int s = (row >> 1) & 3;
    boffl[n][0] = BM * 64 + row * 64 + (((2 * kh + 0) ^ s) << 4);
    boffl[n][1] = BM * 64 + row * 64 + (((2 * kh + 1) ^ s) << 4);
  }

  auto stage = [&](int tile) {
    char* sl = lds + (size_t)(tile % NB) * SLOT;
    #pragma unroll
    for (int i = 0; i < 2; ++i) {  // A: 128 rows x 4 chunks = 512
      const int c = i * 256 + tid;
      const int row = c >> 2, ch = c & 3;
      gload16(Ab + ((size_t)(tile * AROWS + arow0 + row)) * 64 + (ch << 4),
              sl + c * 16);
    }
    #pragma unroll
    for (int i = 0; i < 2; ++i) {  // B: 128 rows x 4 chunks = 512
      const int c = i * 256 + tid;
      const int row = c >> 2, ch = c & 3;
      gload16(Bb + ((size_t)tile * bstride + boff + brow0 + row) * 64 + (ch << 4),
              sl + (BM * 4 + c) * 16);
    }
  };

  auto step = [&](int t, int stage_tile) {
    const char* slp = lds + (size_t)(t % NB) * SLOT;
    i32x8 av[2], bv[2];
    #pragma unroll
    for (int m = 0; m < 2; ++m) {
      int4v p0 = *(const int4v*)(slp + aoff[m][0]);
      int4v p1 = *(const int4v*)(slp + aoff[m][1]);
      av[m][0] = p0[0]; av[m][1] = p0[1]; av[m][2] = p0[2]; av[m][3] = p0[3];
      av[m][4] = p1[0]; av[m][5] = p1[1]; av[m][6] = p1[2]; av[m][7] = p1[3];
    }
    #pragma unroll
    for (int n = 0; n < 2; ++n) {
      int4v p0 = *(const int4v*)(slp + boffl[n][0]);
      int4v p1 = *(const int4v*)(slp + boffl[n][1]);
      bv[n][0] = p0[0]; bv[n][1] = p0[1]; bv[n][2] = p0[2]; bv[n][3] = p0[3];
      bv[n][4] = p1[0]; bv[n][5] = p1[1]; bv[n][6] = p1[2]; bv[n][7] = p1[3];
    }
    if (stage_tile >= 0) stage(stage_tile);
    __builtin_amdgcn_s_setprio(1);
    #pragma unroll
    for (int m = 0; m < 2; ++m)
      #pragma unroll
      for (int n = 0; n < 2; ++n)
        acc[m][n] = __builtin_amdgcn_mfma_scale_f32_32x32x64_f8f6f4(
            av[m], bv[n], acc[m][n], 0, 0, 0, SCL1, 0, SCL1);
    __builtin_amdgcn_s_setprio(0);
  };

  #pragma unroll
  for (int d = 0; d < DEPTH; ++d) stage(d);
  wait_vm<CH * (DEPTH - 1)>();
  barrier_raw();

  #pragma unroll 3
  for (int t = 0; t < NT - DEPTH; ++t) {
    step(t, t + DEPTH);
    wait_vm<CH * (DEPTH - 1)>();
    barrier_raw();
  }
  step(NT - 2, -1);
  wait_vm<0>();
  barrier_raw();
  step(NT - 1, -1);

  if (EPI == 0) {
    // D rows = h (32-frag mapping), cols = px. Pack 4 consecutive-h fp8 per
    // dword; write HID [kt][px][64B] linear-k, chunk^((px>>1)&3).
    const int kt = (arow0 + wm * 64) >> 6;
    #pragma unroll
    for (int m = 0; m < 2; ++m) {
      #pragma unroll
      for (int G = 0; G < 4; ++G) {
        const int bytepos = m * 32 + 8 * G + 4 * kh;         // h within 64B row
        const int hg = arow0 + wm * 64 + bytepos;
        const float b0 = bias[hg + 0], b1v = bias[hg + 1];
        const float b2v = bias[hg + 2], b3v = bias[hg + 3];
        const int chunk = bytepos >> 4, sub = bytepos & 15;
        #pragma unroll
        for (int n = 0; n < 2; ++n) {
          const int px = brow0 + wn * 64 + n * 32 + lane31;
          const int d = pk4(fast_gelu(acc[m][n][4 * G + 0] + b0),
                            fast_gelu(acc[m][n][4 * G + 1] + b1v),
                            fast_gelu(acc[m][n][4 * G + 2] + b2v),
                            fast_gelu(acc[m][n][4 * G + 3] + b3v));
          const int pchunk = chunk ^ ((px >> 1) & 3);
          *(int*)(Hout8 + ((size_t)(kt * hstride + px)) * 64 + pchunk * 16 + sub) = d;
        }
      }
    }
  } else {
    #pragma unroll
    for (int m = 0; m < 2; ++m) {
      #pragma unroll
      for (int G = 0; G < 4; ++G) {
        #pragma unroll
        for (int j = 0; j < 4; ++j) {
          const int c = arow0 + wm * 64 + m * 32 + 8 * G + 4 * kh + j;
          const float gv = gamma[c];
          const float bv = bias[c];
          #pragma unroll
          for (int n = 0; n < 2; ++n) {
            const int px = px0 + brow0 + wn * 64 + n * 32 + lane31;
            const int bb = px >> 10, hw = px & 1023;
            const size_t oi = (((size_t)(bb * 384 + c)) << 10) + hw;
            out[oi] = xres[oi] + gv * (acc[m][n][4 * G + j] + bv);
          }
        }
      }
    }
  }
}

// ------------------------------- launcher ----------------------------------
extern "C" void kernel_launch(void* const* d_in, const int* in_sizes, int n_in,
                              void* d_out, int out_size, void* d_ws, size_t ws_size,
                              hipStream_t stream) {
  (void)in_sizes; (void)n_in; (void)out_size;
  const float* x     = (const float*)d_in[0];
  const float* pe_h  = (const float*)d_in[1];
  const float* w_h   = (const float*)d_in[2];
  const float* b_h   = (const float*)d_in[3];
  const float* pe_w  = (const float*)d_in[4];
  const float* w_w   = (const float*)d_in[5];
  const float* b_w   = (const float*)d_in[6];
  const float* ln_w  = (const float*)d_in[7];
  const float* ln_b  = (const float*)d_in[8];
  const float* w1    = (const float*)d_in[9];
  const float* b1    = (const float*)d_in[10];
  const float* w2    = (const float*)d_in[11];
  const float* b2    = (const float*)d_in[12];
  const float* gamma = (const float*)d_in[13];
  float* out = (float*)d_out;
  char* ws = (char*)d_ws;

  // ws: W1P [0, 0.59M) W2P [0.59M, 1.18M) MU [1.18M, +128K) RS [+128K)
  //     YLNP [1.44M, 14.02M) CONV [14.02M, 39.19M) ; HID overlays CONV
  char*           W1P  = ws;
  char*           W2P  = ws + 589824;
  float*          MU   = (float*)(ws + 1179648);
  float*          RS   = (float*)(ws + 1310720);
  char*           YLNP = ws + 1441792;
  unsigned short* CONV = (unsigned short*)(ws + 14024704);
  char*           HID  = ws + 14024704;

  int G = 32;
  while (G > 2) {
    size_t hid = (size_t)G * 1572864ull;  // G*1024 px * 1536 B
    size_t need = 14024704ull + (hid > 25165824ull ? hid : 25165824ull);
    if (need <= ws_size) break;
    G -= 2;
  }

  constexpr int LDS = (128 + 128) * 64 * 3;  // 49152

  pack_kernel<<<dim3(60), dim3(256), 0, stream>>>(w1, w2, W1P, W2P);
  conv_kernel<<<dim3(1536), dim3(256), 0, stream>>>(x, pe_h, w_h, b_h, pe_w, w_w, b_w, CONV);
  ln_stats_kernel<<<dim3(512), dim3(256), 0, stream>>>(CONV, MU, RS);
  ln_pack_kernel<<<dim3(128, 6), dim3(256), 0, stream>>>(CONV, MU, RS, YLNP, ln_w, ln_b);
  for (int i0 = 0; i0 < 32; i0 += G) {
    const int gi = (32 - i0 < G) ? (32 - i0) : G;
    const int Mpx = gi * 1024;
    // GEMM1: h-blocks 12 (nx), px-blocks Mpx/128. B = YLNP (kt-stride 32768).
    {
      const int nwg = 12 * (Mpx / 128);
      gemm_kernel<0, 384, 1536><<<dim3(nwg), dim3(256), LDS, stream>>>(
          W1P, YLNP, HID, b1, nullptr, nullptr, nullptr,
          0, 32768, i0 * 1024, Mpx, nwg, 12);
    }
    // GEMM2: c-blocks 3 (nx), px-blocks Mpx/128. B = HID (kt-stride Mpx).
    {
      const int nwg = 3 * (Mpx / 128);
      gemm_kernel<1, 1536, 384><<<dim3(nwg), dim3(256), LDS, stream>>>(
          W2P, HID, nullptr, b2, gamma, x, out, i0 * 1024, Mpx, 0, 0, nwg, 3);
    }
  }
}

// Round 11
// 110.583 us; speedup vs baseline: 1.0551x; 1.0551x over previous
//
#include <hip/hip_runtime.h>

// ---------------------------------------------------------------------------
// ParC-ConvNeXt block, MI355X (gfx950).
//   out = x + gamma * MLP(LN(NHWC(concat(ParC_H(x[:192]), ParC_W(x[192:])))))
// Round 10 -> 11:
//   * Conflict-free LDS layout: packed fp8 tensors reordered to
//     [kt][row-group 32][kc-perm {0,2,1,3}][row31]x16B so each wave fragment
//     read is one CONTIGUOUS 1KB ds_read (zero bank conflicts), and staging
//     is identity (src + tid*16 -> lds + tid*16, no address VALU, no XOR).
//   * Occupancy: 512-thr 8-wave blocks (wave tile 32x64, acc f32x16[2]),
//     BM=BN=128, NB=3 ring 48KB, DEPTH=2 counted vmcnt -> 16-24 waves/CU
//     (was ~8-12). MX-scaled fp8 MFMA kept (unit E8M0 scales).
// ---------------------------------------------------------------------------

typedef __attribute__((ext_vector_type(8))) short short8;
typedef __attribute__((ext_vector_type(4))) float f32x4;
typedef __attribute__((ext_vector_type(16))) float f32x16;
typedef __attribute__((ext_vector_type(4))) int int4v;
typedef __attribute__((ext_vector_type(8))) int i32x8;

__device__ __forceinline__ float bf2f(unsigned short u) {
  union { unsigned int i; float f; } v; v.i = ((unsigned int)u) << 16; return v.f;
}
__device__ __forceinline__ unsigned short f2bf(float f) {
  union { float f; unsigned int i; } v; v.f = f;
  unsigned int r = v.i + 0x7FFFu + ((v.i >> 16) & 1u);
  return (unsigned short)(r >> 16);
}

#if defined(__has_builtin)
#if __has_builtin(__builtin_amdgcn_global_load_lds)
#define HAS_GLL 1
#endif
#endif
#ifndef HAS_GLL
#define HAS_GLL 0
#endif

#if HAS_GLL
__device__ __forceinline__ void gload16(const void* g, void* l) {
  __builtin_amdgcn_global_load_lds((const __attribute__((address_space(1))) void*)g,
                                   (__attribute__((address_space(3))) void*)l, 16, 0, 0);
}
#else
__device__ __forceinline__ void gload16(const void* g, void* l) {
  *(f32x4*)l = *(const f32x4*)g;
}
#endif

template <int N>
__device__ __forceinline__ void wait_vm() {
  asm volatile("s_waitcnt vmcnt(%0)" :: "n"(N) : "memory");
}
__device__ __forceinline__ void barrier_raw() {
  __builtin_amdgcn_s_barrier();
  __builtin_amdgcn_sched_barrier(0);
}

// fast sigmoid-GELU: h * sigmoid(1.702h); exp2/rcp HW approx (1e-6 slack)
__device__ __forceinline__ float fast_gelu(float h) {
  const float e = __builtin_amdgcn_exp2f(-2.4554005f * h);  // 1.702/ln2 folded
  return h * __builtin_amdgcn_rcpf(1.f + e);
}

// pack 4 consecutive-k f32 into fp8 dword
__device__ __forceinline__ int pk4(float a, float b, float c, float d) {
  int r = __builtin_amdgcn_cvt_pk_fp8_f32(a, b, 0, false);
  return __builtin_amdgcn_cvt_pk_fp8_f32(c, d, r, true);
}

#define SCL1 0x7F7F7F7F  // E8M0 = 127 -> 2^0 in all 4 bytes

// Packed fragment layout (per kt): byte offset for (row, 16B-k-chunk kc):
//   (row>>5)*2048 + (kc&1)*1024 + (kc>>1)*512 + (row&31)*16
// => per 32-row group: [kc0|kc2|kc1|kc3] halves; a wave's fragment read
// (fixed j, lanes: kh=lane>>5, r=lane&31) is contiguous 1KB.
__device__ __forceinline__ int packed_off(int row, int kc) {
  return ((row >> 5) << 11) + ((kc & 1) << 10) + ((kc >> 1) << 9) + ((row & 31) << 4);
}

// --------------------------- weight pack -----------------------------------
// blocks 0..35 : w1 [384][1536] -> W1P [kt 6][packed h 1536]   (k = input dim)
// blocks 36..59: w2 [1536][384] -> W2P [kt 24][packed c 384]   (k = hidden)
__global__ __launch_bounds__(256) void pack_kernel(
    const float* __restrict__ w1, const float* __restrict__ w2,
    char* __restrict__ w1p, char* __restrict__ w2p) {
  const int t = threadIdx.x;
  const int bid = blockIdx.x;
  float v[64];
  if (bid < 36) {
    const int kt = bid % 6, hg = bid / 6;
    const int h = hg * 256 + t;
    #pragma unroll
    for (int k = 0; k < 64; ++k) v[k] = w1[(size_t)(kt * 64 + k) * 1536 + h];
    char* base = w1p + (size_t)kt * 1536 * 64;
    #pragma unroll
    for (int k0 = 0; k0 < 64; k0 += 4) {
      *(int*)(base + packed_off(h, k0 >> 4) + (k0 & 12)) =
          pk4(v[k0], v[k0 + 1], v[k0 + 2], v[k0 + 3]);
    }
  } else {
    const int kt = bid - 36;
    for (int c = t; c < 384; c += 256) {
      #pragma unroll
      for (int k = 0; k < 64; ++k) v[k] = w2[(size_t)(kt * 64 + k) * 384 + c];
      char* base = w2p + (size_t)kt * 384 * 64;
      #pragma unroll
      for (int k0 = 0; k0 < 64; k0 += 4) {
        *(int*)(base + packed_off(c, k0 >> 4) + (k0 & 12)) =
            pk4(v[k0], v[k0 + 1], v[k0 + 2], v[k0 + 3]);
      }
    }
  }
}

// ------------------------------- ParC conv ---------------------------------
__global__ __launch_bounds__(256) void conv_kernel(
    const float* __restrict__ x,
    const float* __restrict__ pe_h, const float* __restrict__ w_h, const float* __restrict__ b_h,
    const float* __restrict__ pe_w, const float* __restrict__ w_w, const float* __restrict__ b_w,
    unsigned short* __restrict__ convout) {
  __shared__ float wt_s[8][32], pe_s[8][32], pc_s[8][32];
  const int t = threadIdx.x;
  const int bid = blockIdx.x;
  const int b = bid / 48, g = bid % 48;
  const int c0 = g << 3;
  const bool ish = (c0 < 192);
  const int cl = t >> 5, q = t & 31;
  {
    const int c = c0 + cl;
    if (ish) { wt_s[cl][q] = w_h[(c << 5) + q];           pe_s[cl][q] = pe_h[(c << 5) + q]; }
    else     { const int cc = c - 192;
               wt_s[cl][q] = w_w[(cc << 5) + q];          pe_s[cl][q] = pe_w[(cc << 5) + q]; }
  }
  __syncthreads();
  {
    float s = ish ? b_h[c0 + cl] : b_w[c0 + cl - 192];
    #pragma unroll
    for (int i = 0; i < 32; ++i) s += pe_s[cl][(q + i) & 31] * wt_s[cl][i];
    pc_s[cl][q] = s;
  }
  __syncthreads();
  const float* xp = x + ((size_t)(b * 384 + c0 + cl) << 10);
  float col[32];
  if (ish) {
    #pragma unroll
    for (int j = 0; j < 32; ++j) col[j] = xp[(j << 5) + q];
  } else {
    const float* rp = xp + (q << 5);
    #pragma unroll
    for (int j4 = 0; j4 < 8; ++j4) {
      f32x4 v = *(const f32x4*)&rp[j4 << 2];
      col[j4 * 4 + 0] = v[0]; col[j4 * 4 + 1] = v[1];
      col[j4 * 4 + 2] = v[2]; col[j4 * 4 + 3] = v[3];
    }
  }
  float wr[32];
  #pragma unroll
  for (int i = 0; i < 32; ++i) wr[i] = wt_s[cl][i];
  float o[32];
  #pragma unroll
  for (int oo = 0; oo < 32; ++oo) o[oo] = pc_s[cl][oo];
  #pragma unroll
  for (int i = 0; i < 32; ++i)
    #pragma unroll
    for (int oo = 0; oo < 32; ++oo)
      o[oo] = fmaf(col[(oo + i) & 31], wr[i], o[oo]);
  unsigned short* op = convout + ((size_t)(b * 384 + c0 + cl) << 10);
  if (ish) {
    #pragma unroll
    for (int oo = 0; oo < 32; ++oo) op[(oo << 5) + q] = f2bf(o[oo]);
  } else {
    #pragma unroll
    for (int j8 = 0; j8 < 4; ++j8) {
      short8 p;
      #pragma unroll
      for (int j = 0; j < 8; ++j) p[j] = (short)f2bf(o[j8 * 8 + j]);
      *(short8*)&op[(q << 5) + j8 * 8] = p;
    }
  }
}

// --------------------------- LayerNorm stats -------------------------------
__global__ __launch_bounds__(256) void ln_stats_kernel(
    const unsigned short* __restrict__ conv,
    float* __restrict__ mu, float* __restrict__ rs) {
  __shared__ float sums[4][64], sqs[4][64];
  const int tid = threadIdx.x;
  const int lane = tid & 63;
  const int w = tid >> 6;
  const int px = blockIdx.x * 64 + lane;
  const int b = px >> 10, hw = px & 1023;
  const unsigned short* cp = conv + (((size_t)(b * 384 + w * 96)) << 10) + hw;
  float s = 0.f, ss = 0.f;
  #pragma unroll 8
  for (int k = 0; k < 96; ++k) {
    float v = bf2f(cp[(size_t)k << 10]);
    s += v; ss = fmaf(v, v, ss);
  }
  sums[w][lane] = s; sqs[w][lane] = ss;
  __syncthreads();
  if (tid < 64) {
    const float st = sums[0][tid] + sums[1][tid] + sums[2][tid] + sums[3][tid];
    const float sst = sqs[0][tid] + sqs[1][tid] + sqs[2][tid] + sqs[3][tid];
    const float m = st * (1.f / 384.f);
    const float var = sst * (1.f / 384.f) - m * m;
    mu[blockIdx.x * 64 + tid] = m;
    rs[blockIdx.x * 64 + tid] = rsqrtf(var + 1e-6f);
  }
}

// --------------------------- LayerNorm pack --------------------------------
// grid (128, 6): thread = one (px, kt). fp8 YLNP [kt 6][packed px 32768].
__global__ __launch_bounds__(256) void ln_pack_kernel(
    const unsigned short* __restrict__ conv,
    const float* __restrict__ mu, const float* __restrict__ rs,
    char* __restrict__ ylnp,
    const float* __restrict__ ln_w, const float* __restrict__ ln_b) {
  __shared__ float lw[64], lb[64];
  const int kt = blockIdx.y;
  const int t = threadIdx.x;
  if (t < 64) { lw[t] = ln_w[kt * 64 + t]; lb[t] = ln_b[kt * 64 + t]; }
  __syncthreads();
  const int px = blockIdx.x * 256 + t;
  const int b = px >> 10, hw = px & 1023;
  const unsigned short* cp = conv + (((size_t)(b * 384 + kt * 64)) << 10) + hw;
  const float m = mu[px], r = rs[px];
  float ov[64];
  #pragma unroll
  for (int k = 0; k < 64; ++k) {
    const float v = bf2f(cp[(size_t)k << 10]);
    ov[k] = (v - m) * r * lw[k] + lb[k];
  }
  char* base = ylnp + (size_t)kt * 32768 * 64;
  #pragma unroll
  for (int q = 0; q < 4; ++q) {
    int4v d;
    d[0] = pk4(ov[q * 16 + 0],  ov[q * 16 + 1],  ov[q * 16 + 2],  ov[q * 16 + 3]);
    d[1] = pk4(ov[q * 16 + 4],  ov[q * 16 + 5],  ov[q * 16 + 6],  ov[q * 16 + 7]);
    d[2] = pk4(ov[q * 16 + 8],  ov[q * 16 + 9],  ov[q * 16 + 10], ov[q * 16 + 11]);
    d[3] = pk4(ov[q * 16 + 12], ov[q * 16 + 13], ov[q * 16 + 14], ov[q * 16 + 15]);
    *(int4v*)(base + packed_off(px, q)) = d;
  }
}

// --------------------------- GEMM (MX fp8) ---------------------------------
// mfma_scale_f32_32x32x64_f8f6f4, unit scales. 512 thr = 8 waves (4x2);
// wave tile 32x64 (acc f32x16[2]); BM=BN=128, K-tile 64, NB=3 ring DEPTH=2,
// counted vmcnt, raw barriers, setprio, XCD swizzle. Identity staging from
// packed layout; fragment reads are contiguous 1KB per wave (conflict-free).
// EPI 0 (GEMM1): HID fp8 [kt 24][packed px hstride], gelu+pk4 dword stores.
// EPI 1 (GEMM2): out(NCHW f32) = x + gamma*(acc+b2), px-contiguous.
template <int EPI, int KDIM, int AROWS>
__global__ __launch_bounds__(512, 4) void gemm_kernel(
    const char* __restrict__ Ab, const char* __restrict__ Bb,
    char* __restrict__ Hout8, const float* __restrict__ bias,
    const float* __restrict__ gamma, const float* __restrict__ xres,
    float* __restrict__ out, int px0, int bstride, int boff, int hstride,
    int nwg, int nx) {
  extern __shared__ char lds[];
  constexpr int BM = 128, BN = 128;
  constexpr int NB = 3, DEPTH = 2;
  constexpr int NT = KDIM / 64;
  constexpr int SLOT = (BM + BN) * 64;       // 16384
  constexpr int CH = 2;                      // gload16 per thread per stage
  const int tid = threadIdx.x;
  const int lane = tid & 63;
  const int wid = tid >> 6;                  // 0..7
  const int wm = wid >> 1;                   // 0..3: A 32-row group
  const int wn = wid & 1;                    // 0..1: B 64-px half
  const int lane31 = lane & 31;
  const int kh = lane >> 5;
  // bijective XCD swizzle; consecutive logical ids share the B (px) strip
  const int bid = blockIdx.x;
  const int q = nwg >> 3, r = nwg & 7;
  const int xcd = bid & 7, idx = bid >> 3;
  const int lg = (xcd < r ? xcd * (q + 1) : r * (q + 1) + (xcd - r) * q) + idx;
  const int xb = lg % nx, yb = lg / nx;
  const int arow0 = xb * BM;
  const int brow0 = yb * BN;

  f32x16 acc[2] = {};

  // slot-relative fragment read bases (contiguous 1KB per wave per read)
  const int abase  = (wm << 11) + (kh << 9) + (lane31 << 4);
  const int bbase0 = BM * 64 + (((wn << 1) + 0) << 11) + (kh << 9) + (lane31 << 4);
  const int bbase1 = BM * 64 + (((wn << 1) + 1) << 11) + (kh << 9) + (lane31 << 4);

  auto stage = [&](int tile) {
    char* sl = lds + (tile % NB) * SLOT;
    gload16(Ab + ((size_t)tile * AROWS + arow0) * 64 + tid * 16, sl + tid * 16);
    gload16(Bb + ((size_t)tile * bstride + boff + brow0) * 64 + tid * 16,
            sl + BM * 64 + tid * 16);
  };

  auto step = [&](int t, int stage_tile) {
    const char* slp = lds + (t % NB) * SLOT;
    int4v a0  = *(const int4v*)(slp + abase);
    int4v a1  = *(const int4v*)(slp + abase + 1024);
    int4v b00 = *(const int4v*)(slp + bbase0);
    int4v b01 = *(const int4v*)(slp + bbase0 + 1024);
    int4v b10 = *(const int4v*)(slp + bbase1);
    int4v b11 = *(const int4v*)(slp + bbase1 + 1024);
    i32x8 av, bv0, bv1;
    av[0] = a0[0];  av[1] = a0[1];  av[2] = a0[2];  av[3] = a0[3];
    av[4] = a1[0];  av[5] = a1[1];  av[6] = a1[2];  av[7] = a1[3];
    bv0[0] = b00[0]; bv0[1] = b00[1]; bv0[2] = b00[2]; bv0[3] = b00[3];
    bv0[4] = b01[0]; bv0[5] = b01[1]; bv0[6] = b01[2]; bv0[7] = b01[3];
    bv1[0] = b10[0]; bv1[1] = b10[1]; bv1[2] = b10[2]; bv1[3] = b10[3];
    bv1[4] = b11[0]; bv1[5] = b11[1]; bv1[6] = b11[2]; bv1[7] = b11[3];
    if (stage_tile >= 0) stage(stage_tile);
    __builtin_amdgcn_s_setprio(1);
    acc[0] = __builtin_amdgcn_mfma_scale_f32_32x32x64_f8f6f4(
        av, bv0, acc[0], 0, 0, 0, SCL1, 0, SCL1);
    acc[1] = __builtin_amdgcn_mfma_scale_f32_32x32x64_f8f6f4(
        av, bv1, acc[1], 0, 0, 0, SCL1, 0, SCL1);
    __builtin_amdgcn_s_setprio(0);
  };

  #pragma unroll
  for (int d = 0; d < DEPTH; ++d) stage(d);
  wait_vm<CH * (DEPTH - 1)>();
  barrier_raw();

  #pragma unroll 1
  for (int t = 0; t < NT - DEPTH; ++t) {
    step(t, t + DEPTH);
    wait_vm<CH * (DEPTH - 1)>();
    barrier_raw();
  }
  step(NT - 2, -1);
  wait_vm<0>();
  barrier_raw();
  step(NT - 1, -1);

  // D (32x32 frag) mapping: col = lane31, row = (reg&3) + 8*(reg>>2) + 4*kh
  if (EPI == 0) {
    const int kt2 = (arow0 >> 6) + (wm >> 1);
    #pragma unroll
    for (int G = 0; G < 4; ++G) {
      const int hbyte = ((wm & 1) << 5) + 8 * G + 4 * kh;   // h within 64
      const int hglob = arow0 + (wm << 5) + 8 * G + 4 * kh;
      const float c0 = bias[hglob + 0], c1 = bias[hglob + 1];
      const float c2 = bias[hglob + 2], c3 = bias[hglob + 3];
      const int kc = hbyte >> 4, sub = hbyte & 15;
      #pragma unroll
      for (int n = 0; n < 2; ++n) {
        const int px = brow0 + ((wn << 1) + n) * 32 + lane31;
        const int d = pk4(fast_gelu(acc[n][4 * G + 0] + c0),
                          fast_gelu(acc[n][4 * G + 1] + c1),
                          fast_gelu(acc[n][4 * G + 2] + c2),
                          fast_gelu(acc[n][4 * G + 3] + c3));
        *(int*)(Hout8 + (size_t)kt2 * hstride * 64 + packed_off(px, kc) + sub) = d;
      }
    }
  } else {
    #pragma unroll
    for (int G = 0; G < 4; ++G) {
      #pragma unroll
      for (int j = 0; j < 4; ++j) {
        const int c = arow0 + (wm << 5) + 8 * G + 4 * kh + j;
        const float gv = gamma[c];
        const float bvv = bias[c];
        #pragma unroll
        for (int n = 0; n < 2; ++n) {
          const int px = px0 + brow0 + ((wn << 1) + n) * 32 + lane31;
          const int bb = px >> 10, hw = px & 1023;
          const size_t oi = (((size_t)(bb * 384 + c)) << 10) + hw;
          out[oi] = xres[oi] + gv * (acc[n][4 * G + j] + bvv);
        }
      }
    }
  }
}

// ------------------------------- launcher ----------------------------------
extern "C" void kernel_launch(void* const* d_in, const int* in_sizes, int n_in,
                              void* d_out, int out_size, void* d_ws, size_t ws_size,
                              hipStream_t stream) {
  (void)in_sizes; (void)n_in; (void)out_size;
  const float* x     = (const float*)d_in[0];
  const float* pe_h  = (const float*)d_in[1];
  const float* w_h   = (const float*)d_in[2];
  const float* b_h   = (const float*)d_in[3];
  const float* pe_w  = (const float*)d_in[4];
  const float* w_w   = (const float*)d_in[5];
  const float* b_w   = (const float*)d_in[6];
  const float* ln_w  = (const float*)d_in[7];
  const float* ln_b  = (const float*)d_in[8];
  const float* w1    = (const float*)d_in[9];
  const float* b1    = (const float*)d_in[10];
  const float* w2    = (const float*)d_in[11];
  const float* b2    = (const float*)d_in[12];
  const float* gamma = (const float*)d_in[13];
  float* out = (float*)d_out;
  char* ws = (char*)d_ws;

  // ws: W1P [0, 0.59M) W2P [0.59M, 1.18M) MU [1.18M, +128K) RS [+128K)
  //     YLNP [1.44M, 14.02M) CONV [14.02M, 39.19M) ; HID overlays CONV
  char*           W1P  = ws;
  char*           W2P  = ws + 589824;
  float*          MU   = (float*)(ws + 1179648);
  float*          RS   = (float*)(ws + 1310720);
  char*           YLNP = ws + 1441792;
  unsigned short* CONV = (unsigned short*)(ws + 14024704);
  char*           HID  = ws + 14024704;

  int G = 32;
  while (G > 2) {
    size_t hid = (size_t)G * 1572864ull;  // G*1024 px * 1536 B
    size_t need = 14024704ull + (hid > 25165824ull ? hid : 25165824ull);
    if (need <= ws_size) break;
    G -= 2;
  }

  constexpr int LDS = (128 + 128) * 64 * 3;  // 49152

  pack_kernel<<<dim3(60), dim3(256), 0, stream>>>(w1, w2, W1P, W2P);
  conv_kernel<<<dim3(1536), dim3(256), 0, stream>>>(x, pe_h, w_h, b_h, pe_w, w_w, b_w, CONV);
  ln_stats_kernel<<<dim3(512), dim3(256), 0, stream>>>(CONV, MU, RS);
  ln_pack_kernel<<<dim3(128, 6), dim3(256), 0, stream>>>(CONV, MU, RS, YLNP, ln_w, ln_b);
  for (int i0 = 0; i0 < 32; i0 += G) {
    const int gi = (32 - i0 < G) ? (32 - i0) : G;
    const int Mpx = gi * 1024;
    // GEMM1: h-blocks 12 (nx), px-blocks Mpx/128. B = YLNP (kt-stride 32768 rows).
    {
      const int nwg = 12 * (Mpx / 128);
      gemm_kernel<0, 384, 1536><<<dim3(nwg), dim3(512), LDS, stream>>>(
          W1P, YLNP, HID, b1, nullptr, nullptr, nullptr,
          0, 32768, i0 * 1024, Mpx, nwg, 12);
    }
    // GEMM2: c-blocks 3 (nx), px-blocks Mpx/128. B = HID (kt-stride Mpx rows).
    {
      const int nwg = 3 * (Mpx / 128);
      gemm_kernel<1, 1536, 384><<<dim3(nwg), dim3(512), LDS, stream>>>(
          W2P, HID, nullptr, b2, gamma, x, out, i0 * 1024, Mpx, 0, 0, nwg, 3);
    }
  }
}

// Round 12
// 104.833 us; speedup vs baseline: 1.1130x; 1.0548x over previous
//
#include <hip/hip_runtime.h>

// ---------------------------------------------------------------------------
// ParC-ConvNeXt block, MI355X (gfx950).
//   out = x + gamma * MLP(LN(NHWC(concat(ParC_H(x[:192]), ParC_W(x[192:])))))
// Round 11 -> 12:
//   * GEMM1 wave tile 32x256 (BN=256/block, acc f32x16[4]): LDS FLOP/B
//     32 -> 52, prologue/epilogue amortized over 2x output, grid 3072->1536.
//   * Fused single-pass LN: conv strip (64px x 384ch) staged once in LDS
//     (144B row pitch, bank-safe), stats + fp8 fragment-pack from LDS.
//     Saves 25MB HBM reads + one dispatch. MU/RS buffers gone.
//   * GEMM2 / conv / pack unchanged (MX fp8, conflict-free packed layout,
//     NB=3 ring DEPTH=2 counted vmcnt, setprio, XCD swizzle).
// ---------------------------------------------------------------------------

typedef __attribute__((ext_vector_type(8))) short short8;
typedef __attribute__((ext_vector_type(4))) float f32x4;
typedef __attribute__((ext_vector_type(16))) float f32x16;
typedef __attribute__((ext_vector_type(4))) int int4v;
typedef __attribute__((ext_vector_type(8))) int i32x8;

__device__ __forceinline__ float bf2f(unsigned short u) {
  union { unsigned int i; float f; } v; v.i = ((unsigned int)u) << 16; return v.f;
}
__device__ __forceinline__ unsigned short f2bf(float f) {
  union { float f; unsigned int i; } v; v.f = f;
  unsigned int r = v.i + 0x7FFFu + ((v.i >> 16) & 1u);
  return (unsigned short)(r >> 16);
}

#if defined(__has_builtin)
#if __has_builtin(__builtin_amdgcn_global_load_lds)
#define HAS_GLL 1
#endif
#endif
#ifndef HAS_GLL
#define HAS_GLL 0
#endif

#if HAS_GLL
__device__ __forceinline__ void gload16(const void* g, void* l) {
  __builtin_amdgcn_global_load_lds((const __attribute__((address_space(1))) void*)g,
                                   (__attribute__((address_space(3))) void*)l, 16, 0, 0);
}
#else
__device__ __forceinline__ void gload16(const void* g, void* l) {
  *(f32x4*)l = *(const f32x4*)g;
}
#endif

template <int N>
__device__ __forceinline__ void wait_vm() {
  asm volatile("s_waitcnt vmcnt(%0)" :: "n"(N) : "memory");
}
__device__ __forceinline__ void barrier_raw() {
  __builtin_amdgcn_s_barrier();
  __builtin_amdgcn_sched_barrier(0);
}

// fast sigmoid-GELU: h * sigmoid(1.702h); exp2/rcp HW approx (1e-6 slack)
__device__ __forceinline__ float fast_gelu(float h) {
  const float e = __builtin_amdgcn_exp2f(-2.4554005f * h);  // 1.702/ln2 folded
  return h * __builtin_amdgcn_rcpf(1.f + e);
}

// pack 4 consecutive-k f32 into fp8 dword
__device__ __forceinline__ int pk4(float a, float b, float c, float d) {
  int r = __builtin_amdgcn_cvt_pk_fp8_f32(a, b, 0, false);
  return __builtin_amdgcn_cvt_pk_fp8_f32(c, d, r, true);
}

#define SCL1 0x7F7F7F7F  // E8M0 = 127 -> 2^0 in all 4 bytes

// Packed fragment layout (per kt): byte offset for (row, 16B-k-chunk kc):
//   (row>>5)*2048 + (kc&1)*1024 + (kc>>1)*512 + (row&31)*16
__device__ __forceinline__ int packed_off(int row, int kc) {
  return ((row >> 5) << 11) + ((kc & 1) << 10) + ((kc >> 1) << 9) + ((row & 31) << 4);
}

// --------------------------- weight pack -----------------------------------
__global__ __launch_bounds__(256) void pack_kernel(
    const float* __restrict__ w1, const float* __restrict__ w2,
    char* __restrict__ w1p, char* __restrict__ w2p) {
  const int t = threadIdx.x;
  const int bid = blockIdx.x;
  float v[64];
  if (bid < 36) {
    const int kt = bid % 6, hg = bid / 6;
    const int h = hg * 256 + t;
    #pragma unroll
    for (int k = 0; k < 64; ++k) v[k] = w1[(size_t)(kt * 64 + k) * 1536 + h];
    char* base = w1p + (size_t)kt * 1536 * 64;
    #pragma unroll
    for (int k0 = 0; k0 < 64; k0 += 4) {
      *(int*)(base + packed_off(h, k0 >> 4) + (k0 & 12)) =
          pk4(v[k0], v[k0 + 1], v[k0 + 2], v[k0 + 3]);
    }
  } else {
    const int kt = bid - 36;
    for (int c = t; c < 384; c += 256) {
      #pragma unroll
      for (int k = 0; k < 64; ++k) v[k] = w2[(size_t)(kt * 64 + k) * 384 + c];
      char* base = w2p + (size_t)kt * 384 * 64;
      #pragma unroll
      for (int k0 = 0; k0 < 64; k0 += 4) {
        *(int*)(base + packed_off(c, k0 >> 4) + (k0 & 12)) =
            pk4(v[k0], v[k0 + 1], v[k0 + 2], v[k0 + 3]);
      }
    }
  }
}

// ------------------------------- ParC conv ---------------------------------
__global__ __launch_bounds__(256) void conv_kernel(
    const float* __restrict__ x,
    const float* __restrict__ pe_h, const float* __restrict__ w_h, const float* __restrict__ b_h,
    const float* __restrict__ pe_w, const float* __restrict__ w_w, const float* __restrict__ b_w,
    unsigned short* __restrict__ convout) {
  __shared__ float wt_s[8][32], pe_s[8][32], pc_s[8][32];
  const int t = threadIdx.x;
  const int bid = blockIdx.x;
  const int b = bid / 48, g = bid % 48;
  const int c0 = g << 3;
  const bool ish = (c0 < 192);
  const int cl = t >> 5, q = t & 31;
  {
    const int c = c0 + cl;
    if (ish) { wt_s[cl][q] = w_h[(c << 5) + q];           pe_s[cl][q] = pe_h[(c << 5) + q]; }
    else     { const int cc = c - 192;
               wt_s[cl][q] = w_w[(cc << 5) + q];          pe_s[cl][q] = pe_w[(cc << 5) + q]; }
  }
  __syncthreads();
  {
    float s = ish ? b_h[c0 + cl] : b_w[c0 + cl - 192];
    #pragma unroll
    for (int i = 0; i < 32; ++i) s += pe_s[cl][(q + i) & 31] * wt_s[cl][i];
    pc_s[cl][q] = s;
  }
  __syncthreads();
  const float* xp = x + ((size_t)(b * 384 + c0 + cl) << 10);
  float col[32];
  if (ish) {
    #pragma unroll
    for (int j = 0; j < 32; ++j) col[j] = xp[(j << 5) + q];
  } else {
    const float* rp = xp + (q << 5);
    #pragma unroll
    for (int j4 = 0; j4 < 8; ++j4) {
      f32x4 v = *(const f32x4*)&rp[j4 << 2];
      col[j4 * 4 + 0] = v[0]; col[j4 * 4 + 1] = v[1];
      col[j4 * 4 + 2] = v[2]; col[j4 * 4 + 3] = v[3];
    }
  }
  float wr[32];
  #pragma unroll
  for (int i = 0; i < 32; ++i) wr[i] = wt_s[cl][i];
  float o[32];
  #pragma unroll
  for (int oo = 0; oo < 32; ++oo) o[oo] = pc_s[cl][oo];
  #pragma unroll
  for (int i = 0; i < 32; ++i)
    #pragma unroll
    for (int oo = 0; oo < 32; ++oo)
      o[oo] = fmaf(col[(oo + i) & 31], wr[i], o[oo]);
  unsigned short* op = convout + ((size_t)(b * 384 + c0 + cl) << 10);
  if (ish) {
    #pragma unroll
    for (int oo = 0; oo < 32; ++oo) op[(oo << 5) + q] = f2bf(o[oo]);
  } else {
    #pragma unroll
    for (int j8 = 0; j8 < 4; ++j8) {
      short8 p;
      #pragma unroll
      for (int j = 0; j < 8; ++j) p[j] = (short)f2bf(o[j8 * 8 + j]);
      *(short8*)&op[(q << 5) + j8 * 8] = p;
    }
  }
}

// --------------------------- fused LayerNorm -------------------------------
// block = 64-px strip: stage conv[384][64px] in LDS once, stats from LDS,
// fp8 fragment-pack from LDS. grid 512, 256 thr.
__global__ __launch_bounds__(256) void ln_fused_kernel(
    const unsigned short* __restrict__ conv, char* __restrict__ ylnp,
    const float* __restrict__ ln_w, const float* __restrict__ ln_b) {
  __shared__ unsigned short tile[384][72];   // 55296 B (144B pitch, bank-safe)
  __shared__ float lws[384], lbs[384];
  __shared__ float ps[4][64], pq[4][64];
  __shared__ float mus[64], rss[64];
  const int t = threadIdx.x;
  const int pb = blockIdx.x;
  const int b = pb >> 4;
  const int hw0 = (pb & 15) << 6;
  for (int i = t; i < 384; i += 256) { lws[i] = ln_w[i]; lbs[i] = ln_b[i]; }
  #pragma unroll
  for (int i = 0; i < 12; ++i) {
    const int idx = t + i * 256;
    const int c = idx >> 3, j = idx & 7;
    short8 v = *(const short8*)(conv + (((size_t)(b * 384 + c)) << 10) + hw0 + j * 8);
    *(short8*)&tile[c][j * 8] = v;
  }
  __syncthreads();
  {
    const int l = t & 63, qt = t >> 6;
    float s = 0.f, ss = 0.f;
    #pragma unroll
    for (int k = 0; k < 96; ++k) {
      const float v = bf2f(tile[qt * 96 + k][l]);
      s += v; ss = fmaf(v, v, ss);
    }
    ps[qt][l] = s; pq[qt][l] = ss;
  }
  __syncthreads();
  if (t < 64) {
    const float st = ps[0][t] + ps[1][t] + ps[2][t] + ps[3][t];
    const float sq = pq[0][t] + pq[1][t] + pq[2][t] + pq[3][t];
    const float m = st * (1.f / 384.f);
    const float var = sq * (1.f / 384.f) - m * m;
    mus[t] = m; rss[t] = rsqrtf(var + 1e-6f);
  }
  __syncthreads();
  const int l = t & 63, kc = t >> 6;
  const int px = pb * 64 + l;
  const float m = mus[l], r = rss[l];
  #pragma unroll
  for (int kt = 0; kt < 6; ++kt) {
    const int c0 = kt * 64 + kc * 16;
    float ov[16];
    #pragma unroll
    for (int e = 0; e < 16; ++e) {
      const float v = bf2f(tile[c0 + e][l]);
      ov[e] = (v - m) * r * lws[c0 + e] + lbs[c0 + e];
    }
    int4v d;
    d[0] = pk4(ov[0],  ov[1],  ov[2],  ov[3]);
    d[1] = pk4(ov[4],  ov[5],  ov[6],  ov[7]);
    d[2] = pk4(ov[8],  ov[9],  ov[10], ov[11]);
    d[3] = pk4(ov[12], ov[13], ov[14], ov[15]);
    *(int4v*)(ylnp + (size_t)kt * 32768 * 64 + packed_off(px, kc)) = d;
  }
}

// --------------------------- GEMM (MX fp8) ---------------------------------
// mfma_scale_f32_32x32x64_f8f6f4, unit scales. 512 thr = 8 waves (4x2);
// wave tile 32 x (BN/2): FN = BN/64 32x32 frags per wave (acc f32x16[FN]).
// BM=128; K-tile 64; NB=3 ring DEPTH=2, counted vmcnt, raw barriers,
// setprio, XCD swizzle. Identity staging; contiguous-1KB fragment reads.
// EPI 0 (GEMM1, BN=256): HID fp8 [kt 24][packed px hstride], gelu+pk4.
// EPI 1 (GEMM2, BN=128): out(NCHW f32) = x + gamma*(acc+b2).
template <int EPI, int KDIM, int AROWS, int BN>
__global__ __launch_bounds__(512, 4) void gemm_kernel(
    const char* __restrict__ Ab, const char* __restrict__ Bb,
    char* __restrict__ Hout8, const float* __restrict__ bias,
    const float* __restrict__ gamma, const float* __restrict__ xres,
    float* __restrict__ out, int px0, int bstride, int boff, int hstride,
    int nwg, int nx) {
  extern __shared__ char lds[];
  constexpr int BM = 128;
  constexpr int FN = BN / 64;                // 32x32 frags per wave
  constexpr int NB = 3, DEPTH = 2;
  constexpr int NT = KDIM / 64;
  constexpr int SLOT = (BM + BN) * 64;
  constexpr int CH = (BM + BN) * 4 / 512;    // gload16 per thread per stage
  constexpr int BCH = BN * 4 / 512;          // B gload16 per thread
  const int tid = threadIdx.x;
  const int lane = tid & 63;
  const int wid = tid >> 6;                  // 0..7
  const int wm = wid >> 1;                   // 0..3: A 32-row group
  const int wn = wid & 1;                    // 0..1: B half
  const int lane31 = lane & 31;
  const int kh = lane >> 5;
  const int bid = blockIdx.x;
  const int q = nwg >> 3, r = nwg & 7;
  const int xcd = bid & 7, idx = bid >> 3;
  const int lg = (xcd < r ? xcd * (q + 1) : r * (q + 1) + (xcd - r) * q) + idx;
  const int xb = lg % nx, yb = lg / nx;
  const int arow0 = xb * BM;
  const int brow0 = yb * BN;

  f32x16 acc[FN] = {};

  const int abase = (wm << 11) + (kh << 9) + (lane31 << 4);
  int bbase[FN];
  #pragma unroll
  for (int n = 0; n < FN; ++n)
    bbase[n] = BM * 64 + ((wn * FN + n) << 11) + (kh << 9) + (lane31 << 4);

  auto stage = [&](int tile) {
    char* sl = lds + (tile % NB) * SLOT;
    gload16(Ab + ((size_t)tile * AROWS + arow0) * 64 + tid * 16, sl + tid * 16);
    const char* bsrc = Bb + ((size_t)tile * bstride + boff + brow0) * 64;
    #pragma unroll
    for (int i = 0; i < BCH; ++i)
      gload16(bsrc + (i * 512 + tid) * 16, sl + BM * 64 + (i * 512 + tid) * 16);
  };

  auto step = [&](int t, int stage_tile) {
    const char* slp = lds + (t % NB) * SLOT;
    int4v a0 = *(const int4v*)(slp + abase);
    int4v a1 = *(const int4v*)(slp + abase + 1024);
    i32x8 av;
    av[0] = a0[0]; av[1] = a0[1]; av[2] = a0[2]; av[3] = a0[3];
    av[4] = a1[0]; av[5] = a1[1]; av[6] = a1[2]; av[7] = a1[3];
    i32x8 bv[FN];
    #pragma unroll
    for (int n = 0; n < FN; ++n) {
      int4v p0 = *(const int4v*)(slp + bbase[n]);
      int4v p1 = *(const int4v*)(slp + bbase[n] + 1024);
      bv[n][0] = p0[0]; bv[n][1] = p0[1]; bv[n][2] = p0[2]; bv[n][3] = p0[3];
      bv[n][4] = p1[0]; bv[n][5] = p1[1]; bv[n][6] = p1[2]; bv[n][7] = p1[3];
    }
    if (stage_tile >= 0) stage(stage_tile);
    __builtin_amdgcn_s_setprio(1);
    #pragma unroll
    for (int n = 0; n < FN; ++n)
      acc[n] = __builtin_amdgcn_mfma_scale_f32_32x32x64_f8f6f4(
          av, bv[n], acc[n], 0, 0, 0, SCL1, 0, SCL1);
    __builtin_amdgcn_s_setprio(0);
  };

  #pragma unroll
  for (int d = 0; d < DEPTH; ++d) stage(d);
  wait_vm<CH * (DEPTH - 1)>();
  barrier_raw();

  #pragma unroll 1
  for (int t = 0; t < NT - DEPTH; ++t) {
    step(t, t + DEPTH);
    wait_vm<CH * (DEPTH - 1)>();
    barrier_raw();
  }
  step(NT - 2, -1);
  wait_vm<0>();
  barrier_raw();
  step(NT - 1, -1);

  // D (32x32 frag): col = lane31, row = (reg&3) + 8*(reg>>2) + 4*kh
  if (EPI == 0) {
    const int kt2 = (arow0 >> 6) + (wm >> 1);
    #pragma unroll
    for (int G = 0; G < 4; ++G) {
      const int hbyte = ((wm & 1) << 5) + 8 * G + 4 * kh;
      const int hglob = arow0 + (wm << 5) + 8 * G + 4 * kh;
      const float c0 = bias[hglob + 0], c1 = bias[hglob + 1];
      const float c2 = bias[hglob + 2], c3 = bias[hglob + 3];
      const int kc = hbyte >> 4, sub = hbyte & 15;
      #pragma unroll
      for (int n = 0; n < FN; ++n) {
        const int px = brow0 + (wn * FN + n) * 32 + lane31;
        const int d = pk4(fast_gelu(acc[n][4 * G + 0] + c0),
                          fast_gelu(acc[n][4 * G + 1] + c1),
                          fast_gelu(acc[n][4 * G + 2] + c2),
                          fast_gelu(acc[n][4 * G + 3] + c3));
        *(int*)(Hout8 + (size_t)kt2 * hstride * 64 + packed_off(px, kc) + sub) = d;
      }
    }
  } else {
    #pragma unroll
    for (int G = 0; G < 4; ++G) {
      #pragma unroll
      for (int j = 0; j < 4; ++j) {
        const int c = arow0 + (wm << 5) + 8 * G + 4 * kh + j;
        const float gv = gamma[c];
        const float bvv = bias[c];
        #pragma unroll
        for (int n = 0; n < FN; ++n) {
          const int px = px0 + brow0 + (wn * FN + n) * 32 + lane31;
          const int bb = px >> 10, hw = px & 1023;
          const size_t oi = (((size_t)(bb * 384 + c)) << 10) + hw;
          out[oi] = xres[oi] + gv * (acc[n][4 * G + j] + bvv);
        }
      }
    }
  }
}

// ------------------------------- launcher ----------------------------------
extern "C" void kernel_launch(void* const* d_in, const int* in_sizes, int n_in,
                              void* d_out, int out_size, void* d_ws, size_t ws_size,
                              hipStream_t stream) {
  (void)in_sizes; (void)n_in; (void)out_size;
  const float* x     = (const float*)d_in[0];
  const float* pe_h  = (const float*)d_in[1];
  const float* w_h   = (const float*)d_in[2];
  const float* b_h   = (const float*)d_in[3];
  const float* pe_w  = (const float*)d_in[4];
  const float* w_w   = (const float*)d_in[5];
  const float* b_w   = (const float*)d_in[6];
  const float* ln_w  = (const float*)d_in[7];
  const float* ln_b  = (const float*)d_in[8];
  const float* w1    = (const float*)d_in[9];
  const float* b1    = (const float*)d_in[10];
  const float* w2    = (const float*)d_in[11];
  const float* b2    = (const float*)d_in[12];
  const float* gamma = (const float*)d_in[13];
  float* out = (float*)d_out;
  char* ws = (char*)d_ws;

  // ws: W1P [0, 0.59M) W2P [0.59M, 1.18M) YLNP [1.44M, 14.02M)
  //     CONV [14.02M, 39.19M) ; HID overlays CONV
  char*           W1P  = ws;
  char*           W2P  = ws + 589824;
  char*           YLNP = ws + 1441792;
  unsigned short* CONV = (unsigned short*)(ws + 14024704);
  char*           HID  = ws + 14024704;

  int G = 32;
  while (G > 2) {
    size_t hid = (size_t)G * 1572864ull;  // G*1024 px * 1536 B
    size_t need = 14024704ull + (hid > 25165824ull ? hid : 25165824ull);
    if (need <= ws_size) break;
    G -= 2;
  }

  constexpr int LDS1 = (128 + 256) * 64 * 3;  // 73728
  constexpr int LDS2 = (128 + 128) * 64 * 3;  // 49152
  (void)hipFuncSetAttribute((const void*)gemm_kernel<0, 384, 1536, 256>,
                            hipFuncAttributeMaxDynamicSharedMemorySize, LDS1);

  pack_kernel<<<dim3(60), dim3(256), 0, stream>>>(w1, w2, W1P, W2P);
  conv_kernel<<<dim3(1536), dim3(256), 0, stream>>>(x, pe_h, w_h, b_h, pe_w, w_w, b_w, CONV);
  ln_fused_kernel<<<dim3(512), dim3(256), 0, stream>>>(CONV, YLNP, ln_w, ln_b);
  for (int i0 = 0; i0 < 32; i0 += G) {
    const int gi = (32 - i0 < G) ? (32 - i0) : G;
    const int Mpx = gi * 1024;
    // GEMM1: h-blocks 12 (nx), px-blocks Mpx/256. B = YLNP (kt-stride 32768 rows).
    {
      const int nwg = 12 * (Mpx / 256);
      gemm_kernel<0, 384, 1536, 256><<<dim3(nwg), dim3(512), LDS1, stream>>>(
          W1P, YLNP, HID, b1, nullptr, nullptr, nullptr,
          0, 32768, i0 * 1024, Mpx, nwg, 12);
    }
    // GEMM2: c-blocks 3 (nx), px-blocks Mpx/128. B = HID (kt-stride Mpx rows).
    {
      const int nwg = 3 * (Mpx / 128);
      gemm_kernel<1, 1536, 384, 128><<<dim3(nwg), dim3(512), LDS2, stream>>>(
          W2P, HID, nullptr, b2, gamma, x, out, i0 * 1024, Mpx, 0, 0, nwg, 3);
    }
  }
}

// Round 13
// 100.270 us; speedup vs baseline: 1.1637x; 1.0455x over previous
//
#include <hip/hip_runtime.h>

// ---------------------------------------------------------------------------
// ParC-ConvNeXt block, MI355X (gfx950).
//   out = x + gamma * MLP(LN(NHWC(concat(ParC_H(x[:192]), ParC_W(x[192:])))))
// Round 12 -> 13: LDS-pipe rebalance. ds_read_b128 ~12 CU-cyc vs 32x32x64
//   MX MFMA ~69 SIMD-cyc -> need LDS-reads/MFMA R = 2(FM+FN)/(FM*FN) <= ~1.4.
//   Wave tiles squared to FM=2,FN=2 (64x64, acc f32x16[2][2], R: 3->2):
//   GEMM1 512thr 2x4 waves BM128xBN256 (72KB, 2 blk/CU, grid 1536);
//   GEMM2 256thr 2x2 waves BM128xBN128 (48KB, 3 blk/CU, grid 768).
//   All layouts/producers unchanged (MX fp8, conflict-free packed fragments,
//   identity staging, NB=3 ring DEPTH=2 counted vmcnt, setprio, XCD swizzle).
// ---------------------------------------------------------------------------

typedef __attribute__((ext_vector_type(8))) short short8;
typedef __attribute__((ext_vector_type(4))) float f32x4;
typedef __attribute__((ext_vector_type(16))) float f32x16;
typedef __attribute__((ext_vector_type(4))) int int4v;
typedef __attribute__((ext_vector_type(8))) int i32x8;

__device__ __forceinline__ float bf2f(unsigned short u) {
  union { unsigned int i; float f; } v; v.i = ((unsigned int)u) << 16; return v.f;
}
__device__ __forceinline__ unsigned short f2bf(float f) {
  union { float f; unsigned int i; } v; v.f = f;
  unsigned int r = v.i + 0x7FFFu + ((v.i >> 16) & 1u);
  return (unsigned short)(r >> 16);
}

#if defined(__has_builtin)
#if __has_builtin(__builtin_amdgcn_global_load_lds)
#define HAS_GLL 1
#endif
#endif
#ifndef HAS_GLL
#define HAS_GLL 0
#endif

#if HAS_GLL
__device__ __forceinline__ void gload16(const void* g, void* l) {
  __builtin_amdgcn_global_load_lds((const __attribute__((address_space(1))) void*)g,
                                   (__attribute__((address_space(3))) void*)l, 16, 0, 0);
}
#else
__device__ __forceinline__ void gload16(const void* g, void* l) {
  *(f32x4*)l = *(const f32x4*)g;
}
#endif

template <int N>
__device__ __forceinline__ void wait_vm() {
  asm volatile("s_waitcnt vmcnt(%0)" :: "n"(N) : "memory");
}
__device__ __forceinline__ void barrier_raw() {
  __builtin_amdgcn_s_barrier();
  __builtin_amdgcn_sched_barrier(0);
}

// fast sigmoid-GELU: h * sigmoid(1.702h); exp2/rcp HW approx (1e-6 slack)
__device__ __forceinline__ float fast_gelu(float h) {
  const float e = __builtin_amdgcn_exp2f(-2.4554005f * h);  // 1.702/ln2 folded
  return h * __builtin_amdgcn_rcpf(1.f + e);
}

// pack 4 consecutive-k f32 into fp8 dword
__device__ __forceinline__ int pk4(float a, float b, float c, float d) {
  int r = __builtin_amdgcn_cvt_pk_fp8_f32(a, b, 0, false);
  return __builtin_amdgcn_cvt_pk_fp8_f32(c, d, r, true);
}

#define SCL1 0x7F7F7F7F  // E8M0 = 127 -> 2^0 in all 4 bytes

// Packed fragment layout (per kt): byte offset for (row, 16B-k-chunk kc):
//   (row>>5)*2048 + (kc&1)*1024 + (kc>>1)*512 + (row&31)*16
__device__ __forceinline__ int packed_off(int row, int kc) {
  return ((row >> 5) << 11) + ((kc & 1) << 10) + ((kc >> 1) << 9) + ((row & 31) << 4);
}

// --------------------------- weight pack -----------------------------------
__global__ __launch_bounds__(256) void pack_kernel(
    const float* __restrict__ w1, const float* __restrict__ w2,
    char* __restrict__ w1p, char* __restrict__ w2p) {
  const int t = threadIdx.x;
  const int bid = blockIdx.x;
  float v[64];
  if (bid < 36) {
    const int kt = bid % 6, hg = bid / 6;
    const int h = hg * 256 + t;
    #pragma unroll
    for (int k = 0; k < 64; ++k) v[k] = w1[(size_t)(kt * 64 + k) * 1536 + h];
    char* base = w1p + (size_t)kt * 1536 * 64;
    #pragma unroll
    for (int k0 = 0; k0 < 64; k0 += 4) {
      *(int*)(base + packed_off(h, k0 >> 4) + (k0 & 12)) =
          pk4(v[k0], v[k0 + 1], v[k0 + 2], v[k0 + 3]);
    }
  } else {
    const int kt = bid - 36;
    for (int c = t; c < 384; c += 256) {
      #pragma unroll
      for (int k = 0; k < 64; ++k) v[k] = w2[(size_t)(kt * 64 + k) * 384 + c];
      char* base = w2p + (size_t)kt * 384 * 64;
      #pragma unroll
      for (int k0 = 0; k0 < 64; k0 += 4) {
        *(int*)(base + packed_off(c, k0 >> 4) + (k0 & 12)) =
            pk4(v[k0], v[k0 + 1], v[k0 + 2], v[k0 + 3]);
      }
    }
  }
}

// ------------------------------- ParC conv ---------------------------------
__global__ __launch_bounds__(256) void conv_kernel(
    const float* __restrict__ x,
    const float* __restrict__ pe_h, const float* __restrict__ w_h, const float* __restrict__ b_h,
    const float* __restrict__ pe_w, const float* __restrict__ w_w, const float* __restrict__ b_w,
    unsigned short* __restrict__ convout) {
  __shared__ float wt_s[8][32], pe_s[8][32], pc_s[8][32];
  const int t = threadIdx.x;
  const int bid = blockIdx.x;
  const int b = bid / 48, g = bid % 48;
  const int c0 = g << 3;
  const bool ish = (c0 < 192);
  const int cl = t >> 5, q = t & 31;
  {
    const int c = c0 + cl;
    if (ish) { wt_s[cl][q] = w_h[(c << 5) + q];           pe_s[cl][q] = pe_h[(c << 5) + q]; }
    else     { const int cc = c - 192;
               wt_s[cl][q] = w_w[(cc << 5) + q];          pe_s[cl][q] = pe_w[(cc << 5) + q]; }
  }
  __syncthreads();
  {
    float s = ish ? b_h[c0 + cl] : b_w[c0 + cl - 192];
    #pragma unroll
    for (int i = 0; i < 32; ++i) s += pe_s[cl][(q + i) & 31] * wt_s[cl][i];
    pc_s[cl][q] = s;
  }
  __syncthreads();
  const float* xp = x + ((size_t)(b * 384 + c0 + cl) << 10);
  float col[32];
  if (ish) {
    #pragma unroll
    for (int j = 0; j < 32; ++j) col[j] = xp[(j << 5) + q];
  } else {
    const float* rp = xp + (q << 5);
    #pragma unroll
    for (int j4 = 0; j4 < 8; ++j4) {
      f32x4 v = *(const f32x4*)&rp[j4 << 2];
      col[j4 * 4 + 0] = v[0]; col[j4 * 4 + 1] = v[1];
      col[j4 * 4 + 2] = v[2]; col[j4 * 4 + 3] = v[3];
    }
  }
  float wr[32];
  #pragma unroll
  for (int i = 0; i < 32; ++i) wr[i] = wt_s[cl][i];
  float o[32];
  #pragma unroll
  for (int oo = 0; oo < 32; ++oo) o[oo] = pc_s[cl][oo];
  #pragma unroll
  for (int i = 0; i < 32; ++i)
    #pragma unroll
    for (int oo = 0; oo < 32; ++oo)
      o[oo] = fmaf(col[(oo + i) & 31], wr[i], o[oo]);
  unsigned short* op = convout + ((size_t)(b * 384 + c0 + cl) << 10);
  if (ish) {
    #pragma unroll
    for (int oo = 0; oo < 32; ++oo) op[(oo << 5) + q] = f2bf(o[oo]);
  } else {
    #pragma unroll
    for (int j8 = 0; j8 < 4; ++j8) {
      short8 p;
      #pragma unroll
      for (int j = 0; j < 8; ++j) p[j] = (short)f2bf(o[j8 * 8 + j]);
      *(short8*)&op[(q << 5) + j8 * 8] = p;
    }
  }
}

// --------------------------- fused LayerNorm -------------------------------
__global__ __launch_bounds__(256) void ln_fused_kernel(
    const unsigned short* __restrict__ conv, char* __restrict__ ylnp,
    const float* __restrict__ ln_w, const float* __restrict__ ln_b) {
  __shared__ unsigned short tile[384][72];   // 55296 B (144B pitch, bank-safe)
  __shared__ float lws[384], lbs[384];
  __shared__ float ps[4][64], pq[4][64];
  __shared__ float mus[64], rss[64];
  const int t = threadIdx.x;
  const int pb = blockIdx.x;
  const int b = pb >> 4;
  const int hw0 = (pb & 15) << 6;
  for (int i = t; i < 384; i += 256) { lws[i] = ln_w[i]; lbs[i] = ln_b[i]; }
  #pragma unroll
  for (int i = 0; i < 12; ++i) {
    const int idx = t + i * 256;
    const int c = idx >> 3, j = idx & 7;
    short8 v = *(const short8*)(conv + (((size_t)(b * 384 + c)) << 10) + hw0 + j * 8);
    *(short8*)&tile[c][j * 8] = v;
  }
  __syncthreads();
  {
    const int l = t & 63, qt = t >> 6;
    float s = 0.f, ss = 0.f;
    #pragma unroll
    for (int k = 0; k < 96; ++k) {
      const float v = bf2f(tile[qt * 96 + k][l]);
      s += v; ss = fmaf(v, v, ss);
    }
    ps[qt][l] = s; pq[qt][l] = ss;
  }
  __syncthreads();
  if (t < 64) {
    const float st = ps[0][t] + ps[1][t] + ps[2][t] + ps[3][t];
    const float sq = pq[0][t] + pq[1][t] + pq[2][t] + pq[3][t];
    const float m = st * (1.f / 384.f);
    const float var = sq * (1.f / 384.f) - m * m;
    mus[t] = m; rss[t] = rsqrtf(var + 1e-6f);
  }
  __syncthreads();
  const int l = t & 63, kc = t >> 6;
  const int px = pb * 64 + l;
  const float m = mus[l], r = rss[l];
  #pragma unroll
  for (int kt = 0; kt < 6; ++kt) {
    const int c0 = kt * 64 + kc * 16;
    float ov[16];
    #pragma unroll
    for (int e = 0; e < 16; ++e) {
      const float v = bf2f(tile[c0 + e][l]);
      ov[e] = (v - m) * r * lws[c0 + e] + lbs[c0 + e];
    }
    int4v d;
    d[0] = pk4(ov[0],  ov[1],  ov[2],  ov[3]);
    d[1] = pk4(ov[4],  ov[5],  ov[6],  ov[7]);
    d[2] = pk4(ov[8],  ov[9],  ov[10], ov[11]);
    d[3] = pk4(ov[12], ov[13], ov[14], ov[15]);
    *(int4v*)(ylnp + (size_t)kt * 32768 * 64 + packed_off(px, kc)) = d;
  }
}

// --------------------------- GEMM (MX fp8) ---------------------------------
// mfma_scale_f32_32x32x64_f8f6f4, unit scales. NWN*128 threads = 2*NWN waves
// as 2(wm) x NWN(wn); wave tile 64x64: acc f32x16[2][2], R = 2 LDS-reads/MFMA.
// BM=128, BN=NWN*64; K-tile 64; NB=3 ring DEPTH=2, counted vmcnt, raw
// barriers, setprio, XCD swizzle. Identity staging; contiguous-1KB reads.
// EPI 0 (GEMM1, NWN=4): HID fp8 [kt 24][packed px hstride], gelu+pk4.
// EPI 1 (GEMM2, NWN=2): out(NCHW f32) = x + gamma*(acc+b2).
template <int EPI, int KDIM, int AROWS, int NWN>
__global__ __launch_bounds__(NWN * 128, 4) void gemm_kernel(
    const char* __restrict__ Ab, const char* __restrict__ Bb,
    char* __restrict__ Hout8, const float* __restrict__ bias,
    const float* __restrict__ gamma, const float* __restrict__ xres,
    float* __restrict__ out, int px0, int bstride, int boff, int hstride,
    int nwg, int nx) {
  extern __shared__ char lds[];
  constexpr int BM = 128;
  constexpr int BN = NWN * 64;
  constexpr int THREADS = NWN * 128;
  constexpr int NB = 3, DEPTH = 2;
  constexpr int NT = KDIM / 64;
  constexpr int SLOT = (BM + BN) * 64;
  constexpr int ACH = BM * 4 / THREADS;      // A gload16 per thread
  constexpr int BCH = BN * 4 / THREADS;      // B gload16 per thread
  constexpr int CH = ACH + BCH;
  const int tid = threadIdx.x;
  const int lane = tid & 63;
  const int wid = tid >> 6;
  const int wm = wid / NWN;                  // 0..1: A 64-row half
  const int wn = wid % NWN;                  // B 64-px group
  const int lane31 = lane & 31;
  const int kh = lane >> 5;
  const int bid = blockIdx.x;
  const int q = nwg >> 3, r = nwg & 7;
  const int xcd = bid & 7, idx = bid >> 3;
  const int lg = (xcd < r ? xcd * (q + 1) : r * (q + 1) + (xcd - r) * q) + idx;
  const int xb = lg % nx, yb = lg / nx;
  const int arow0 = xb * BM;
  const int brow0 = yb * BN;

  f32x16 acc[2][2] = {};

  int abase[2], bbase[2];
  #pragma unroll
  for (int fm = 0; fm < 2; ++fm)
    abase[fm] = ((wm * 2 + fm) << 11) + (kh << 9) + (lane31 << 4);
  #pragma unroll
  for (int n = 0; n < 2; ++n)
    bbase[n] = BM * 64 + ((wn * 2 + n) << 11) + (kh << 9) + (lane31 << 4);

  auto stage = [&](int tile) {
    char* sl = lds + (tile % NB) * SLOT;
    const char* asrc = Ab + ((size_t)tile * AROWS + arow0) * 64;
    #pragma unroll
    for (int i = 0; i < ACH; ++i)
      gload16(asrc + (i * THREADS + tid) * 16, sl + (i * THREADS + tid) * 16);
    const char* bsrc = Bb + ((size_t)tile * bstride + boff + brow0) * 64;
    #pragma unroll
    for (int i = 0; i < BCH; ++i)
      gload16(bsrc + (i * THREADS + tid) * 16, sl + BM * 64 + (i * THREADS + tid) * 16);
  };

  auto step = [&](int t, int stage_tile) {
    const char* slp = lds + (t % NB) * SLOT;
    i32x8 av[2], bv[2];
    #pragma unroll
    for (int fm = 0; fm < 2; ++fm) {
      int4v p0 = *(const int4v*)(slp + abase[fm]);
      int4v p1 = *(const int4v*)(slp + abase[fm] + 1024);
      av[fm][0] = p0[0]; av[fm][1] = p0[1]; av[fm][2] = p0[2]; av[fm][3] = p0[3];
      av[fm][4] = p1[0]; av[fm][5] = p1[1]; av[fm][6] = p1[2]; av[fm][7] = p1[3];
    }
    #pragma unroll
    for (int n = 0; n < 2; ++n) {
      int4v p0 = *(const int4v*)(slp + bbase[n]);
      int4v p1 = *(const int4v*)(slp + bbase[n] + 1024);
      bv[n][0] = p0[0]; bv[n][1] = p0[1]; bv[n][2] = p0[2]; bv[n][3] = p0[3];
      bv[n][4] = p1[0]; bv[n][5] = p1[1]; bv[n][6] = p1[2]; bv[n][7] = p1[3];
    }
    if (stage_tile >= 0) stage(stage_tile);
    __builtin_amdgcn_s_setprio(1);
    #pragma unroll
    for (int fm = 0; fm < 2; ++fm)
      #pragma unroll
      for (int n = 0; n < 2; ++n)
        acc[fm][n] = __builtin_amdgcn_mfma_scale_f32_32x32x64_f8f6f4(
            av[fm], bv[n], acc[fm][n], 0, 0, 0, SCL1, 0, SCL1);
    __builtin_amdgcn_s_setprio(0);
  };

  #pragma unroll
  for (int d = 0; d < DEPTH; ++d) stage(d);
  wait_vm<CH * (DEPTH - 1)>();
  barrier_raw();

  #pragma unroll 1
  for (int t = 0; t < NT - DEPTH; ++t) {
    step(t, t + DEPTH);
    wait_vm<CH * (DEPTH - 1)>();
    barrier_raw();
  }
  step(NT - 2, -1);
  wait_vm<0>();
  barrier_raw();
  step(NT - 1, -1);

  // D (32x32 frag): col = lane31, row = (reg&3) + 8*(reg>>2) + 4*kh
  if (EPI == 0) {
    #pragma unroll
    for (int fm = 0; fm < 2; ++fm) {
      const int wmf = wm * 2 + fm;
      const int kt2 = (arow0 >> 6) + (wmf >> 1);
      #pragma unroll
      for (int G = 0; G < 4; ++G) {
        const int hbyte = ((wmf & 1) << 5) + 8 * G + 4 * kh;
        const int hglob = arow0 + (wmf << 5) + 8 * G + 4 * kh;
        const float c0 = bias[hglob + 0], c1 = bias[hglob + 1];
        const float c2 = bias[hglob + 2], c3 = bias[hglob + 3];
        const int kc = hbyte >> 4, sub = hbyte & 15;
        #pragma unroll
        for (int n = 0; n < 2; ++n) {
          const int px = brow0 + wn * 64 + n * 32 + lane31;
          const int d = pk4(fast_gelu(acc[fm][n][4 * G + 0] + c0),
                            fast_gelu(acc[fm][n][4 * G + 1] + c1),
                            fast_gelu(acc[fm][n][4 * G + 2] + c2),
                            fast_gelu(acc[fm][n][4 * G + 3] + c3));
          *(int*)(Hout8 + (size_t)kt2 * hstride * 64 + packed_off(px, kc) + sub) = d;
        }
      }
    }
  } else {
    #pragma unroll
    for (int fm = 0; fm < 2; ++fm) {
      const int wmf = wm * 2 + fm;
      #pragma unroll
      for (int G = 0; G < 4; ++G) {
        #pragma unroll
        for (int j = 0; j < 4; ++j) {
          const int c = arow0 + (wmf << 5) + 8 * G + 4 * kh + j;
          const float gv = gamma[c];
          const float bvv = bias[c];
          #pragma unroll
          for (int n = 0; n < 2; ++n) {
            const int px = px0 + brow0 + wn * 64 + n * 32 + lane31;
            const int bb = px >> 10, hw = px & 1023;
            const size_t oi = (((size_t)(bb * 384 + c)) << 10) + hw;
            out[oi] = xres[oi] + gv * (acc[fm][n][4 * G + j] + bvv);
          }
        }
      }
    }
  }
}

// ------------------------------- launcher ----------------------------------
extern "C" void kernel_launch(void* const* d_in, const int* in_sizes, int n_in,
                              void* d_out, int out_size, void* d_ws, size_t ws_size,
                              hipStream_t stream) {
  (void)in_sizes; (void)n_in; (void)out_size;
  const float* x     = (const float*)d_in[0];
  const float* pe_h  = (const float*)d_in[1];
  const float* w_h   = (const float*)d_in[2];
  const float* b_h   = (const float*)d_in[3];
  const float* pe_w  = (const float*)d_in[4];
  const float* w_w   = (const float*)d_in[5];
  const float* b_w   = (const float*)d_in[6];
  const float* ln_w  = (const float*)d_in[7];
  const float* ln_b  = (const float*)d_in[8];
  const float* w1    = (const float*)d_in[9];
  const float* b1    = (const float*)d_in[10];
  const float* w2    = (const float*)d_in[11];
  const float* b2    = (const float*)d_in[12];
  const float* gamma = (const float*)d_in[13];
  float* out = (float*)d_out;
  char* ws = (char*)d_ws;

  // ws: W1P [0, 0.59M) W2P [0.59M, 1.18M) YLNP [1.44M, 14.02M)
  //     CONV [14.02M, 39.19M) ; HID overlays CONV
  char*           W1P  = ws;
  char*           W2P  = ws + 589824;
  char*           YLNP = ws + 1441792;
  unsigned short* CONV = (unsigned short*)(ws + 14024704);
  char*           HID  = ws + 14024704;

  int G = 32;
  while (G > 2) {
    size_t hid = (size_t)G * 1572864ull;  // G*1024 px * 1536 B
    size_t need = 14024704ull + (hid > 25165824ull ? hid : 25165824ull);
    if (need <= ws_size) break;
    G -= 2;
  }

  constexpr int LDS1 = (128 + 256) * 64 * 3;  // 73728
  constexpr int LDS2 = (128 + 128) * 64 * 3;  // 49152
  (void)hipFuncSetAttribute((const void*)gemm_kernel<0, 384, 1536, 4>,
                            hipFuncAttributeMaxDynamicSharedMemorySize, LDS1);

  pack_kernel<<<dim3(60), dim3(256), 0, stream>>>(w1, w2, W1P, W2P);
  conv_kernel<<<dim3(1536), dim3(256), 0, stream>>>(x, pe_h, w_h, b_h, pe_w, w_w, b_w, CONV);
  ln_fused_kernel<<<dim3(512), dim3(256), 0, stream>>>(CONV, YLNP, ln_w, ln_b);
  for (int i0 = 0; i0 < 32; i0 += G) {
    const int gi = (32 - i0 < G) ? (32 - i0) : G;
    const int Mpx = gi * 1024;
    // GEMM1: h-blocks 12 (nx), px-blocks Mpx/256. B = YLNP (kt-stride 32768 rows).
    {
      const int nwg = 12 * (Mpx / 256);
      gemm_kernel<0, 384, 1536, 4><<<dim3(nwg), dim3(512), LDS1, stream>>>(
          W1P, YLNP, HID, b1, nullptr, nullptr, nullptr,
          0, 32768, i0 * 1024, Mpx, nwg, 12);
    }
    // GEMM2: c-blocks 3 (nx), px-blocks Mpx/128. B = HID (kt-stride Mpx rows).
    {
      const int nwg = 3 * (Mpx / 128);
      gemm_kernel<1, 1536, 384, 2><<<dim3(nwg), dim3(256), LDS2, stream>>>(
          W2P, HID, nullptr, b2, gamma, x, out, i0 * 1024, Mpx, 0, 0, nwg, 3);
    }
  }
}